// Round 12
// baseline (652.548 us; speedup 1.0000x reference)
//
#include <hip/hip_runtime.h>

#define T 500
#define NB 256
#define VROWS 50001
#define EMB 200
#define KPAD 224
#define LOG2E 1.44269504f

typedef unsigned short u16;
typedef __attribute__((ext_vector_type(8))) __bf16 bf16x8;
typedef __attribute__((ext_vector_type(8))) short short8;
typedef __attribute__((ext_vector_type(8))) u16 u16x8;
typedef __attribute__((ext_vector_type(4))) float f32x4;
typedef __attribute__((ext_vector_type(4))) u16 u16x4;

#define AS1 __attribute__((address_space(1)))
#define AS3 __attribute__((address_space(3)))

__device__ __forceinline__ u16 f2bf(float x) {
  __bf16 h = (__bf16)x;
  return __builtin_bit_cast(u16, h);
}
__device__ __forceinline__ float bf2f(u16 b) {
  union { unsigned u; float f; } v; v.u = ((unsigned)b) << 16;
  return v.f;
}
__device__ __forceinline__ float rcp_(float x) { return __builtin_amdgcn_rcpf(x); }
__device__ __forceinline__ float ex2_(float x) { return __builtin_amdgcn_exp2f(x); }
// gate scales: sig(x)=rcp(1+exp2(-LOG2E*x)); tanh(x)=1-2*rcp(1+exp2(2*LOG2E*x))
__device__ __forceinline__ float gsc(int g) { return (g == 1) ? 2.f * LOG2E : -LOG2E; }

// ---------------------------------------------------------------- prep ------
// Bt[dir][colp][KPAD] bf16 (pre-scaled Wx^T, zero rows for k>=EMB),
// Cproj[dir][cap][colp] f32 (pre-scaled bias + forget_bias + cap one-hot).
__global__ void prep_kernel(const float* __restrict__ cap_emb,
                            const float* __restrict__ Wfw, const float* __restrict__ bfw,
                            const float* __restrict__ Wbw, const float* __restrict__ bbw,
                            float* __restrict__ Cproj, u16* __restrict__ Bt) {
  const int S2 = 2 * 512 * KPAD;
  const int S3 = 2 * 4 * 512;
  int tid = blockIdx.x * blockDim.x + threadIdx.x;
  int nthr = gridDim.x * blockDim.x;
  for (int i = tid; i < S2 + S3; i += nthr) {
    if (i < S2) {
      int d = i / (512 * KPAD), rem = i - d * (512 * KPAD);
      int colp = rem / KPAD, k = rem - colp * KPAD;
      const float* W = d ? Wbw : Wfw;
      int g = colp & 3, jj = colp >> 2;
      Bt[i] = (k < EMB) ? f2bf(W[k * 512 + g * 128 + jj] * gsc(g)) : (u16)0;
    } else {
      int idx = i - S2;
      int dir = idx >> 11; int c = (idx >> 9) & 3; int colp = idx & 511;
      int j = colp >> 2, g = colp & 3;
      const float* W = dir ? Wbw : Wfw;
      const float* bias = dir ? bbw : bfw;
      float v = bias[g * 128 + j] + (g == 2 ? 1.f : 0.f);   // fold forget_bias
      #pragma unroll
      for (int cc = 0; cc < 3; ++cc)
        v += cap_emb[c * 3 + cc] * W[(200 + cc) * 512 + g * 128 + j];
      Cproj[idx] = v * gsc(g);
    }
  }
}

// ------------------------------------------------------------ XP GEMM -------
// XP[dir][t][b][colp] = bf16( emb(words[b][t]) @ Wx_scaled[:,colp]
//                             + Cproj[dir][caps[b][t]][colp] )
// Persistent-A: 1000 blocks (one per 128-token M-tile), 512 threads.
// A staged to LDS ONCE (65 KB, swizzled); then 8 (dir,nt) combos reuse it,
// each staging only the L2-resident Bt slice via global_load_lds.
__global__ __launch_bounds__(512) void xproj_kernel(
    const int* __restrict__ words, const int* __restrict__ caps,
    const float* __restrict__ word_emb, const u16* __restrict__ Bt,
    const float* __restrict__ Cproj, u16* __restrict__ XP) {
  const int mt = blockIdx.x;            // 0..999
  const int tblk = mt >> 1;
  const int bbase = (mt & 1) * 128;

  __shared__ __align__(16) u16 As[128 * 256];       // 64 KB, persists
  __shared__ __align__(16) char pool[34048];        // Bs dbuf (16 KB) / Cls alias
  u16* Bs = (u16*)pool;
  float (*Cls)[132] = (float(*)[132])pool;

  const int tid = threadIdx.x;
  const int w = tid >> 6, l = tid & 63;
  const int la = l & 15, lb = l >> 4;
  const int wr = w >> 1, wc = w & 1;                // 4x2 wave grid

  // ---- A stage (once): 128 rows x 28 chunks(8k) , swizzle chunk^((row&7)) ----
  for (int i = tid; i < 128 * 28; i += 512) {
    int r = i / 28, c = i - r * 28;
    u16x8 o;
    if (c < 25) {
      int wd = words[(bbase + r) * T + tblk];
      const float* p = word_emb + (size_t)wd * EMB + c * 8;
      f32x4 v0 = *(const f32x4*)p;
      f32x4 v1 = *(const f32x4*)(p + 4);
      #pragma unroll
      for (int e = 0; e < 4; ++e) { o[e] = f2bf(v0[e]); o[4 + e] = f2bf(v1[e]); }
    } else {
      o = u16x8{0,0,0,0,0,0,0,0};
    }
    *(u16x8*)&As[r * 256 + ((c ^ (r & 7)) * 8)] = o;
  }
  __syncthreads();

  // ---- B staging lane constants: slot s = w*64+l; dest chunk d=s&3, row rn=s>>2;
  //      source chunk c = d ^ (rn&3) (involution, matches read-side XOR) ----
  const int s_ = w * 64 + l;
  const int brn = s_ >> 2, bd = s_ & 3;
  const int bc = bd ^ (brn & 3);

  const int rrow = tid >> 2, rch = tid & 3;         // epilogue assignment
  const int rb = bbase + rrow;
  const int rcap = caps[rb * T + tblk];

  #pragma unroll 1
  for (int combo = 0; combo < 8; ++combo) {
    const int dir = combo >> 2, nt = combo & 3;
    const u16* __restrict__ B = Bt + (size_t)dir * 512 * KPAD;
    u16* __restrict__ xp = XP + (size_t)dir * T * NB * 512;
    const int n0 = nt * 128;
    const u16* bsrc = B + (size_t)(n0 + brn) * KPAD + bc * 8;

    auto stageB = [&](int buf, int ks) {
      __builtin_amdgcn_global_load_lds(
          (const AS1 void*)(bsrc + ks * 32),
          (AS3 void*)&Bs[buf * 4096 + w * 512], 16, 0, 0);
    };

    f32x4 z = {0.f, 0.f, 0.f, 0.f};
    f32x4 acc[2][4] = {{z,z,z,z},{z,z,z,z}};

    stageB(0, 0);
    __syncthreads();
    #pragma unroll 1
    for (int ks = 0; ks < 7; ++ks) {
      const int cur = ks & 1;
      if (ks < 6) stageB(cur ^ 1, ks + 1);
      bf16x8 af[2], bfr[4];
      #pragma unroll
      for (int m = 0; m < 2; ++m) {
        int ra = wr * 32 + m * 16 + la;
        af[m] = *(const bf16x8*)&As[ra * 256 + (((ks * 4 + lb) ^ (ra & 7)) * 8)];
      }
      #pragma unroll
      for (int n = 0; n < 4; ++n) {
        int rn = wc * 64 + n * 16 + la;
        bfr[n] = *(const bf16x8*)&Bs[cur * 4096 + rn * 32 + ((lb ^ (rn & 3)) * 8)];
      }
      #pragma unroll
      for (int m = 0; m < 2; ++m)
        #pragma unroll
        for (int n = 0; n < 4; ++n)
          acc[m][n] = __builtin_amdgcn_mfma_f32_16x16x32_bf16(af[m], bfr[n], acc[m][n], 0, 0, 0);
      __syncthreads();
    }

    // epilogue: two N-half passes through Cls (aliases Bs; barriers separate)
    const float* __restrict__ cbase = Cproj + (dir * 4 + rcap) * 512;
    u16* __restrict__ rop = xp + ((size_t)tblk * NB + rb) * 512;
    #pragma unroll
    for (int pass = 0; pass < 2; ++pass) {
      if (wc == pass) {
        #pragma unroll
        for (int m = 0; m < 2; ++m)
          #pragma unroll
          for (int n = 0; n < 4; ++n)
            *(f32x4*)&Cls[n * 16 + la][wr * 32 + m * 16 + lb * 4] = acc[m][n];
      }
      __syncthreads();
      int colp0 = n0 + pass * 64 + rch * 16;
      #pragma unroll
      for (int s = 0; s < 2; ++s) {
        u16x8 o;
        #pragma unroll
        for (int e = 0; e < 8; ++e) {
          int cl = rch * 16 + s * 8 + e;
          o[e] = f2bf(Cls[cl][rrow] + cbase[colp0 + s * 8 + e]);
        }
        *(u16x8*)(rop + colp0 + s * 8) = o;
      }
      __syncthreads();
    }
  }
}

// ------------------------------------------------------------ LSTM ----------
// 8 waves (512 thr), 32 blocks (16 batch rows x 2 dir).  Operand-swapped MFMA:
// D[j][batch] -> lane (la,lb) owns batch la, j = w*16+lb*4+r.  xp = 2 contiguous
// u16x8 loads; h-write = single b64; rnn-write = f32x4.
template <int PAR>
__device__ __forceinline__ void lstm_step(
    int t, int dir, int la, int lb, int w,
    const u16* __restrict__ xpd, int voff,
    const bf16x8 (&bfrag)[4][4], u16* __restrict__ hbuf,
    u16x8 (&xc)[2],            // data for t (consume)
    u16x8 (&xg)[2],            // load target for t+2
    f32x4& cst, f32x4& hl) {
  // B fragments (h_prev, batch la) from swizzled LDS
  const u16* hb = hbuf + PAR * 2048;
  const int swz = (la & 7) << 3;
  bf16x8 afr[4];
  #pragma unroll
  for (int kk = 0; kk < 4; ++kk)
    afr[kk] = *(const bf16x8*)(hb + ((la * 128 + kk * 32 + lb * 8) ^ swz));

  // issue xp loads for t+2 (2 contiguous 16B loads)
  {
    int ts = t + 2; if (ts > T - 1) ts = T - 1;
    int tt = dir ? (T - 1 - ts) : ts;
    const u16* p = xpd + (size_t)tt * (NB * 512) + voff;
    xg[0] = *(const u16x8*)p;
    xg[1] = *(const u16x8*)(p + 8);
  }

  // accumulators = x-projection; local colp index = r*4+g
  f32x4 acc0, acc1, acc2, acc3;
  #pragma unroll
  for (int r = 0; r < 4; ++r) {
    const u16x8& xh = (r < 2) ? xc[0] : xc[1];
    int base = (r & 1) * 4;
    acc0[r] = bf2f(xh[base + 0]);
    acc1[r] = bf2f(xh[base + 1]);
    acc2[r] = bf2f(xh[base + 2]);
    acc3[r] = bf2f(xh[base + 3]);
  }
  // gates += Wh^T-block @ h  (swapped operands -> D[j][batch])
  __builtin_amdgcn_s_setprio(1);
  #pragma unroll
  for (int kk = 0; kk < 4; ++kk) {
    acc0 = __builtin_amdgcn_mfma_f32_16x16x32_bf16(bfrag[0][kk], afr[kk], acc0, 0, 0, 0);
    acc1 = __builtin_amdgcn_mfma_f32_16x16x32_bf16(bfrag[1][kk], afr[kk], acc1, 0, 0, 0);
    acc2 = __builtin_amdgcn_mfma_f32_16x16x32_bf16(bfrag[2][kk], afr[kk], acc2, 0, 0, 0);
    acc3 = __builtin_amdgcn_mfma_f32_16x16x32_bf16(bfrag[3][kk], afr[kk], acc3, 0, 0, 0);
  }
  __builtin_amdgcn_s_setprio(0);
  // cell update — 7 trans/cell; single b64 h-write (row la, 4 consecutive j)
  u16* ho = hbuf + (PAR ^ 1) * 2048;
  u16x4 hw;
  #pragma unroll
  for (int r = 0; r < 4; ++r) {
    float ei = ex2_(acc0[r]);
    float ej = ex2_(acc1[r]);
    float ef = ex2_(acc2[r]);
    float eo = ex2_(acc3[r]);
    float pij = (1.f + ei) * (1.f + ej);
    float pf  = 1.f + ef;
    float num = cst[r] * pij + (ej - 1.f) * pf;
    float cn  = num * rcp_(pij * pf);
    cst[r] = cn;
    float E = ex2_(2.f * LOG2E * cn);
    float hn = (E - 1.f) * rcp_((1.f + eo) * (1.f + E));
    hl[r] = hn;
    hw[r] = f2bf(hn);
  }
  *(u16x4*)&ho[(la * 128 + w * 16 + lb * 4) ^ swz] = hw;
  // LDS-only drain + raw barrier: vmcnt NOT drained, xp loads stay in flight
  __builtin_amdgcn_sched_barrier(0);
  asm volatile("s_waitcnt lgkmcnt(0)");
  __builtin_amdgcn_s_barrier();
  __builtin_amdgcn_sched_barrier(0);
}

__global__ __launch_bounds__(512, 1) void lstm_kernel(
    const u16* __restrict__ XP, const float* __restrict__ Wfw,
    const float* __restrict__ Wbw, float* __restrict__ rnn) {
  const int dir = blockIdx.x & 1;
  const int chunk = blockIdx.x >> 1;
  const int b0 = chunk * 16;
  const u16* __restrict__ xpd = XP + (size_t)dir * T * NB * 512;
  const float* __restrict__ W = dir ? Wbw : Wfw;

  const int tid = threadIdx.x;
  const int w = tid >> 6, l = tid & 63, la = l & 15, lb = l >> 4;
  const int j = w * 16 + la;

  // per-lane xp offset (u16 units): batch row b0+la, colp base (w*16+lb*4)*4
  const int voff = (b0 + la) * 512 + w * 64 + lb * 16;

  // Wh fragments (pre-scaled): A-operand row la <-> j = w*16+la (unchanged code)
  bf16x8 bfrag[4][4];
  #pragma unroll
  for (int g = 0; g < 4; ++g) {
    #pragma unroll
    for (int kk = 0; kk < 4; ++kk) {
      short8 t8;
      #pragma unroll
      for (int r = 0; r < 8; ++r) {
        int k = kk * 32 + lb * 8 + r;
        t8[r] = (short)f2bf(W[(203 + k) * 512 + g * 128 + j] * gsc(g));
      }
      bfrag[g][kk] = __builtin_bit_cast(bf16x8, t8);
    }
  }

  __shared__ u16 hbuf[2 * 16 * 128];
  for (int i = tid; i < 2 * 16 * 128; i += 512) hbuf[i] = 0;

  f32x4 cst = {0.f, 0.f, 0.f, 0.f};
  f32x4 hl  = {0.f, 0.f, 0.f, 0.f};

  u16x8 xA[2], xB[2], xC[2], xD[2];
  {
    int tt0 = dir ? (T - 1) : 0;
    int tt1 = dir ? (T - 2) : 1;
    const u16* p0 = xpd + (size_t)tt0 * (NB * 512) + voff;
    const u16* p1 = xpd + (size_t)tt1 * (NB * 512) + voff;
    xA[0] = *(const u16x8*)p0; xA[1] = *(const u16x8*)(p0 + 8);
    xB[0] = *(const u16x8*)p1; xB[1] = *(const u16x8*)(p1 + 8);
  }
  __syncthreads();

  #pragma unroll 1
  for (int tq = 0; tq < T / 4; ++tq) {
    int t0 = 4 * tq;
    lstm_step<0>(t0,     dir, la, lb, w, xpd, voff, bfrag, hbuf, xA, xC, cst, hl);
    lstm_step<1>(t0 + 1, dir, la, lb, w, xpd, voff, bfrag, hbuf, xB, xD, cst, hl);
    lstm_step<0>(t0 + 2, dir, la, lb, w, xpd, voff, bfrag, hbuf, xC, xA, cst, hl);
    lstm_step<1>(t0 + 3, dir, la, lb, w, xpd, voff, bfrag, hbuf, xD, xB, cst, hl);
  }

  // lane holds h_final for batch b0+la, j = w*16+lb*4+r  -> coalesced f32x4
  *(f32x4*)&rnn[(size_t)(b0 + la) * 256 + dir * 128 + w * 16 + lb * 4] = hl;
}

// ------------------------------------------------------------ head ----------
__global__ void head_kernel(const float* __restrict__ rnn, const float* __restrict__ W1,
                            const float* __restrict__ b1, const float* __restrict__ W2,
                            const float* __restrict__ b2, float* __restrict__ out) {
  int b = blockIdx.x;
  int jj = threadIdx.x;  // 64 threads
  __shared__ float d1[64];
  float acc = b1[jj];
  const float* r = rnn + b * 256;
  #pragma unroll 4
  for (int k = 0; k < 256; ++k) acc += r[k] * W1[k * 64 + jj];
  d1[jj] = acc > 0.f ? acc : (__expf(acc) - 1.f);
  __syncthreads();
  if (jj < 6) {
    float a2 = b2[jj];
    #pragma unroll 8
    for (int k = 0; k < 64; ++k) a2 += d1[k] * W2[k * 6 + jj];
    out[b * 6 + jj] = rcp_(1.f + __expf(-a2));
  }
}

// ------------------------------------------------------------ launch --------
extern "C" void kernel_launch(void* const* d_in, const int* in_sizes, int n_in,
                              void* d_out, int out_size, void* d_ws, size_t ws_size,
                              hipStream_t stream) {
  (void)in_sizes; (void)n_in; (void)out_size; (void)ws_size;
  const int*   words    = (const int*)  d_in[0];
  const int*   caps     = (const int*)  d_in[1];
  const float* word_emb = (const float*)d_in[2];
  const float* cap_emb  = (const float*)d_in[3];
  const float* Wfw      = (const float*)d_in[4];
  const float* bfw      = (const float*)d_in[5];
  const float* Wbw      = (const float*)d_in[6];
  const float* bbw      = (const float*)d_in[7];
  const float* W1       = (const float*)d_in[8];
  const float* b1       = (const float*)d_in[9];
  const float* W2       = (const float*)d_in[10];
  const float* b2       = (const float*)d_in[11];
  float* out = (float*)d_out;

  char* base = (char*)d_ws;
  size_t off = 0;
  auto alloc = [&](size_t bytes) {
    char* q = base + off;
    off = (off + bytes + 255) & ~(size_t)255;
    return q;
  };
  u16*   XP     = (u16*)  alloc((size_t)2 * T * NB * 512 * 2);   // 262.1 MB
  u16*   Bt     = (u16*)  alloc((size_t)2 * 512 * KPAD * 2);
  float* Cproj  = (float*)alloc((size_t)2 * 4 * 512 * 4);
  float* rnn    = (float*)alloc((size_t)256 * 256 * 4);
  // total ~262.9 MB == R7-proven budget.

  hipLaunchKernelGGL(prep_kernel, dim3(256), dim3(256), 0, stream,
                     cap_emb, Wfw, bfw, Wbw, bbw, Cproj, Bt);
  hipLaunchKernelGGL(xproj_kernel, dim3(1000), dim3(512), 0, stream,
                     words, caps, word_emb, Bt, Cproj, XP);
  hipLaunchKernelGGL(lstm_kernel, dim3(32), dim3(512), 0, stream,
                     XP, Wfw, Wbw, rnn);
  hipLaunchKernelGGL(head_kernel, dim3(256), dim3(64), 0, stream,
                     rnn, W1, b1, W2, b2, out);
}